// Round 1
// 174.130 us; speedup vs baseline: 1.1451x; 1.1451x over previous
//
#include <hip/hip_runtime.h>
#include <math.h>

// ---------------------------------------------------------------------------
// FPSANConv2d: out = conv3x3(x, Qt(w)) + b + sigmoid(gate)*(conv3x3(x, Qt(w_child)) + b_child)
// Fused: W_eff = Qt(w) + g*Qt(w_child) (bf16), b_eff = b + g*b_child, ONE conv.
//
// Round 6 (this round): conv_mfma rebuilt around LDS staging.
//   Theory: VGPR=72 proved the compiler de-pipelined the per-tap global A/B
//   prefetch -> serial load->MFMA chains at L2/HBM latency (L1 thrashed by
//   50KB/block working set). Fix: stage the block's 4 padded input rows into
//   LDS once (reg-staged ds_write_b128, chunk-XOR swizzle q^(px&7) to kill the
//   16-way px-stride bank conflict), feed all 9 taps from LDS. B stays global
//   (L1-hot broadcast) with 1-tap register prefetch. setprio around MFMAs.
//   k1/k2/k3 unchanged.
// ---------------------------------------------------------------------------

typedef __attribute__((ext_vector_type(8))) short short8;   // 8 bf16 (4 VGPRs)
typedef __attribute__((ext_vector_type(4))) float float4v;  // MFMA C/D frag

__device__ inline unsigned short f2bf(float f) {
  union { float f; unsigned u; } v; v.f = f;
  unsigned u = v.u;
  return (unsigned short)((u + 0x7FFFu + ((u >> 16) & 1u)) >> 16);  // RNE
}

// ---- k1: deterministic partial |w| sums: 9 blocks x 1024 x 4 elems ----
__global__ __launch_bounds__(1024) void reduce_abs_part(const float* __restrict__ w,
                                                        const float* __restrict__ wc,
                                                        double* __restrict__ part) {
  const int base = blockIdx.x * 4096 + threadIdx.x;
  double a = 0.0, c = 0.0;
#pragma unroll
  for (int i = 0; i < 4; ++i) {
    a += (double)fabsf(w[base + i * 1024]);
    c += (double)fabsf(wc[base + i * 1024]);
  }
#pragma unroll
  for (int off = 32; off > 0; off >>= 1) {
    a += __shfl_down(a, off);
    c += __shfl_down(c, off);
  }
  __shared__ double sa[16], sc[16];
  int wv = threadIdx.x >> 6;
  if ((threadIdx.x & 63) == 0) { sa[wv] = a; sc[wv] = c; }
  __syncthreads();
  if (threadIdx.x == 0) {
    double ta = 0.0, tc = 0.0;
#pragma unroll
    for (int i = 0; i < 16; ++i) { ta += sa[i]; tc += sc[i]; }
    part[blockIdx.x] = ta;
    part[9 + blockIdx.x] = tc;
  }
}

// ---- k2: ternary-quantize both weights, combine with gate, emit bf16 ----
// wq[tap][oc][ci], tap = kh*3+kw : ci-contiguous for 16B B-fragment loads.
__global__ void quant_combine(const float* __restrict__ w, const float* __restrict__ wc,
                              const float* __restrict__ b, const float* __restrict__ bc,
                              const float* __restrict__ gate, const double* __restrict__ part,
                              unsigned short* __restrict__ wq, float* __restrict__ beff) {
  double s0 = 0.0, s1 = 0.0;
#pragma unroll
  for (int i = 0; i < 9; ++i) { s0 += part[i]; s1 += part[9 + i]; }
  const float sw = fmaxf((float)(s0 * (1.0 / 36864.0)), 1e-5f);
  const float sc = fmaxf((float)(s1 * (1.0 / 36864.0)), 1e-5f);
  const float g = 1.0f / (1.0f + expf(-gate[0]));
  int idx = blockIdx.x * 256 + threadIdx.x;  // (tap, oc, ci)
  int tap = idx >> 12;
  int oc = (idx >> 6) & 63;
  int ci = idx & 63;
  int src = oc * 576 + ci * 9 + tap;  // OIHW flat
  float q1 = fminf(1.f, fmaxf(-1.f, rintf(w[src] / sw))) * sw;
  float q2 = fminf(1.f, fmaxf(-1.f, rintf(wc[src] / sc))) * sc;
  wq[idx] = f2bf(q1 + g * q2);
  if (idx < 64) beff[idx] = b[idx] + g * bc[idx];
}

// ---- k3: NCHW f32 -> zero-padded NHWC bf16  x_p[n][hp 0..129][cp 0..129][ci] ----
// Odd-stride (33 dword) LDS tile: conflict-free writes & reads, coalesced global IO.
__global__ __launch_bounds__(256) void transpose_x(const float* __restrict__ x,
                                                   unsigned short* __restrict__ xp) {
  const int bid = blockIdx.x;            // n*130 + hp
  const int n = bid / 130;
  const int hp = bid - n * 130;
  unsigned short* dst = xp + (size_t)(n * 130 + hp) * (130 * 64);
  const int tid = threadIdx.x;

  if (hp == 0 || hp == 129) {            // zero whole padded row (1040 x 16B)
    for (int j = tid; j < 1040; j += 256) ((short8*)dst)[j] = (short8)0;
    return;
  }
  const int h = hp - 1;
  __shared__ unsigned tile[128 * 33];    // [c][ci-pair], stride 33 dwords (odd)

  const float* src = x + (size_t)n * 64 * 16384 + h * 128;
  for (int k = tid; k < 4096; k += 256) {  // ci-pair major, c inner (coalesced)
    int ci2 = k >> 7;                      // 0..31
    int c = k & 127;
    unsigned lo = f2bf(src[(2 * ci2) * 16384 + c]);
    unsigned hi = f2bf(src[(2 * ci2 + 1) * 16384 + c]);
    tile[c * 33 + ci2] = lo | (hi << 16);  // bank (c+ci2)%32: 2-way, free
  }
  // zero col borders (cp=0 and cp=129)
  if (tid < 8) ((short8*)dst)[tid] = (short8)0;
  else if (tid < 16) ((short8*)dst)[1032 + (tid - 8)] = (short8)0;
  __syncthreads();
  // interior: lanes write contiguous 16B -> 1KB/wave stores
  for (int j = tid; j < 1024; j += 256) {
    int c = j >> 3;
    int q = j & 7;
    const unsigned* tp = &tile[c * 33 + q * 4];
    unsigned u0 = tp[0], u1 = tp[1], u2 = tp[2], u3 = tp[3];  // conflict-free
    short8 v;
    v[0] = (short)(u0 & 0xffff); v[1] = (short)(u0 >> 16);
    v[2] = (short)(u1 & 0xffff); v[3] = (short)(u1 >> 16);
    v[4] = (short)(u2 & 0xffff); v[5] = (short)(u2 >> 16);
    v[6] = (short)(u3 & 0xffff); v[7] = (short)(u3 >> 16);
    ((short8*)dst)[8 + j] = v;  // cp = c+1
  }
}

// ---- k4: conv as implicit GEMM; wave = 64px x 64oc; block = 2 rows ----
// XCD-ownership swizzle: XCD (bid&7) processes 2 complete images, so all halo
// sharing happens inside one XCD's 4MB L2 (zero cross-XCD duplication).
// LDS: 4 padded rows [r 0..3][px 0..129][ci 0..63] bf16 = 66,560 B, stored as
// 16B chunks with chunk' = q ^ (px&7) swizzle (both write & read sides) so
// ds_read_b128 A-fragments hit all 32 banks 2-way (free) instead of 16-way.
// -> 2 blocks/CU (LDS-limited); one stages while the other runs MFMAs.
__global__ __launch_bounds__(256, 2) void conv_mfma(
    const unsigned short* __restrict__ xp, const unsigned short* __restrict__ wq,
    const float* __restrict__ beff, float* __restrict__ out) {
  extern __shared__ __align__(16) char smem[];  // 66,560 B
  const int bid = blockIdx.x;        // 1024 blocks
  const int xcd = bid & 7;
  const int u = bid >> 3;            // 0..127
  const int n = xcd * 2 + (u >> 6);  // XCD owns images 2*xcd, 2*xcd+1
  const int h0 = (u & 63) * 2;       // output rows h0, h0+1
  const int tid = threadIdx.x;
  const int lane = tid & 63;
  const int wv = tid >> 6;
  const int rw = wv >> 1;            // which output row (0/1)
  const int pxh = (wv & 1) * 64;     // pixel half
  const int ln15 = lane & 15;
  const int lq = lane >> 4;          // 0..3: 16B ci-chunk within 64B half
  const int koff = lq << 3;          // shorts

  // ---- stage padded rows h0..h0+3 into LDS (chunk-XOR swizzled) ----
  // slab is contiguous in xp: 4 rows x 130 px x 128 B = 4160 16B chunks.
  const unsigned short* slab = xp + (size_t)(n * 130 + h0) * (130 * 64);
  for (int j = tid; j < 4160; j += 256) {
    int r = j / 1040;                // row 0..3
    int rem = j - r * 1040;
    int p = rem >> 3;                // px 0..129
    int q = rem & 7;                 // 16B chunk within px
    short8 v = *(const short8*)(slab + j * 8);
    *(short8*)(smem + ((r * 1040 + (p << 3) + (q ^ (p & 7))) << 4)) = v;
  }
  __syncthreads();

  const unsigned short* wbase = wq + ln15 * 64 + koff;

  short8 A[2][2][4], B[2][2][4];
  float4v acc[4][4] = {};  // [mf][qd]

  auto load_tap = [&](int tap, short8 Ab[2][4], short8 Bb[2][4]) {
    const int dh = tap / 3;
    const int dw = tap - dh * 3;
    const int r = rw + dh;                 // LDS row 0..3
    const int pb = pxh + ln15 + dw;        // px for mf=0 (px&7 invariant in mf)
    const int swz = lq ^ (pb & 7);         // swizzled chunk for cc2=0
    const int b0 = ((r * 130 + pb) << 7) + (swz << 4);
    const unsigned short* wp = wbase + tap * 4096;
#pragma unroll
    for (int mf = 0; mf < 4; ++mf) {       // px += 16 per mf: swizzle unchanged
      Ab[0][mf] = *(const short8*)(smem + (b0 + mf * 2048));
      Ab[1][mf] = *(const short8*)(smem + ((b0 ^ 64) + mf * 2048));  // cc2=1: chunk^4
    }
#pragma unroll
    for (int qd = 0; qd < 4; ++qd) {
      Bb[0][qd] = *(const short8*)(wp + qd * 1024);
      Bb[1][qd] = *(const short8*)(wp + qd * 1024 + 32);
    }
  };

  load_tap(0, A[0], B[0]);
#pragma unroll
  for (int tap = 0; tap < 9; ++tap) {
    const int cur = tap & 1, nxt = cur ^ 1;
    if (tap < 8) load_tap(tap + 1, A[nxt], B[nxt]);
    __builtin_amdgcn_s_setprio(1);
#pragma unroll
    for (int cc2 = 0; cc2 < 2; ++cc2)
#pragma unroll
      for (int mf = 0; mf < 4; ++mf)
#pragma unroll
        for (int qd = 0; qd < 4; ++qd)
          acc[mf][qd] = __builtin_amdgcn_mfma_f32_16x16x32_bf16(
              A[cur][cc2][mf], B[cur][cc2][qd], acc[mf][qd], 0, 0, 0);
    __builtin_amdgcn_s_setprio(0);
  }

  // epilogue: C/D layout col=lane&15 (oc), row=(lane>>4)*4+reg (pixel)
  const int rq = lane >> 4;
  float bias[4];
#pragma unroll
  for (int q = 0; q < 4; ++q) bias[q] = beff[q * 16 + ln15];
#pragma unroll
  for (int mf = 0; mf < 4; ++mf) {
#pragma unroll
    for (int qd = 0; qd < 4; ++qd) {
      float4v v = acc[mf][qd] + bias[qd];
      int oc = qd * 16 + ln15;
      float* op = out + (((n * 64 + oc) * 128 + h0 + rw) * 128 + pxh + mf * 16 + rq * 4);
      *(float4v*)op = v;
    }
  }
}

extern "C" void kernel_launch(void* const* d_in, const int* in_sizes, int n_in,
                              void* d_out, int out_size, void* d_ws, size_t ws_size,
                              hipStream_t stream) {
  const float* x = (const float*)d_in[0];
  const float* w = (const float*)d_in[1];
  const float* b = (const float*)d_in[2];
  const float* wc = (const float*)d_in[3];
  const float* bc = (const float*)d_in[4];
  const float* gate = (const float*)d_in[5];

  // ws: wq bf16[36864]=73728B | beff f32[64] @73728 | part f64[18] @73984
  //     | x_p bf16[16*130*130*64]=34611200B @74240
  unsigned short* wq = (unsigned short*)d_ws;
  float* beff = (float*)((char*)d_ws + 73728);
  double* part = (double*)((char*)d_ws + 73984);
  unsigned short* xp = (unsigned short*)((char*)d_ws + 74240);

  transpose_x<<<16 * 130, 256, 0, stream>>>(x, xp);
  reduce_abs_part<<<9, 1024, 0, stream>>>(w, wc, part);
  quant_combine<<<144, 256, 0, stream>>>(w, wc, b, bc, gate, part, wq, beff);
  conv_mfma<<<16 * 64, 256, 66560, stream>>>(xp, wq, beff, (float*)d_out);
}

// Round 3
// 165.815 us; speedup vs baseline: 1.2025x; 1.0501x over previous
//
#include <hip/hip_runtime.h>
#include <math.h>

// ---------------------------------------------------------------------------
// FPSANConv2d: out = conv3x3(x, Qt(w)) + b + sigmoid(gate)*(conv3x3(x, Qt(w_child)) + b_child)
// Fused: W_eff = Qt(w) + g*Qt(w_child) (bf16), b_eff = b + g*b_child, ONE conv.
//
// Round 8 = Round 7 resubmit (container failed twice = infra flake, no verdict).
//   transpose_x ELIMINATED. conv stages directly from NCHW f32 x,
//   doing the bf16 convert + NHWC swizzle in the staging loop (identical RNE
//   conversion -> bit-identical numerics). Kills the 100MB xp round-trip, a
//   2080-block kernel, and one launch gap (~117us of non-conv time in R6).
//   Staging: per (row,ci-chunk) pass a wave reads 64 px x 4B = 256B coalesced
//   dwords, packs short8, chunk-XOR-swizzled ds_write_b128 (2-way banks, free).
//   Zero-pad rows/cols handled by block-uniform predication.
//   Tap loop / MFMA structure unchanged from R6 (verified correct).
// ---------------------------------------------------------------------------

typedef __attribute__((ext_vector_type(8))) short short8;   // 8 bf16 (4 VGPRs)
typedef __attribute__((ext_vector_type(4))) float float4v;  // MFMA C/D frag

__device__ inline unsigned short f2bf(float f) {
  union { float f; unsigned u; } v; v.f = f;
  unsigned u = v.u;
  return (unsigned short)((u + 0x7FFFu + ((u >> 16) & 1u)) >> 16);  // RNE
}

// ---- k1: deterministic partial |w| sums: 9 blocks x 1024 x 4 elems ----
__global__ __launch_bounds__(1024) void reduce_abs_part(const float* __restrict__ w,
                                                        const float* __restrict__ wc,
                                                        double* __restrict__ part) {
  const int base = blockIdx.x * 4096 + threadIdx.x;
  double a = 0.0, c = 0.0;
#pragma unroll
  for (int i = 0; i < 4; ++i) {
    a += (double)fabsf(w[base + i * 1024]);
    c += (double)fabsf(wc[base + i * 1024]);
  }
#pragma unroll
  for (int off = 32; off > 0; off >>= 1) {
    a += __shfl_down(a, off);
    c += __shfl_down(c, off);
  }
  __shared__ double sa[16], sc[16];
  int wv = threadIdx.x >> 6;
  if ((threadIdx.x & 63) == 0) { sa[wv] = a; sc[wv] = c; }
  __syncthreads();
  if (threadIdx.x == 0) {
    double ta = 0.0, tc = 0.0;
#pragma unroll
    for (int i = 0; i < 16; ++i) { ta += sa[i]; tc += sc[i]; }
    part[blockIdx.x] = ta;
    part[9 + blockIdx.x] = tc;
  }
}

// ---- k2: ternary-quantize both weights, combine with gate, emit bf16 ----
// wq[tap][oc][ci], tap = kh*3+kw : ci-contiguous for 16B B-fragment loads.
__global__ void quant_combine(const float* __restrict__ w, const float* __restrict__ wc,
                              const float* __restrict__ b, const float* __restrict__ bc,
                              const float* __restrict__ gate, const double* __restrict__ part,
                              unsigned short* __restrict__ wq, float* __restrict__ beff) {
  double s0 = 0.0, s1 = 0.0;
#pragma unroll
  for (int i = 0; i < 9; ++i) { s0 += part[i]; s1 += part[9 + i]; }
  const float sw = fmaxf((float)(s0 * (1.0 / 36864.0)), 1e-5f);
  const float sc = fmaxf((float)(s1 * (1.0 / 36864.0)), 1e-5f);
  const float g = 1.0f / (1.0f + expf(-gate[0]));
  int idx = blockIdx.x * 256 + threadIdx.x;  // (tap, oc, ci)
  int tap = idx >> 12;
  int oc = (idx >> 6) & 63;
  int ci = idx & 63;
  int src = oc * 576 + ci * 9 + tap;  // OIHW flat
  float q1 = fminf(1.f, fmaxf(-1.f, rintf(w[src] / sw))) * sw;
  float q2 = fminf(1.f, fmaxf(-1.f, rintf(wc[src] / sc))) * sc;
  wq[idx] = f2bf(q1 + g * q2);
  if (idx < 64) beff[idx] = b[idx] + g * bc[idx];
}

// ---- k3: fused conv: NCHW f32 -> LDS bf16 staging + implicit-GEMM MFMA ----
// wave = 64px x 64oc; block = 2 output rows; 1024 blocks.
// XCD-ownership swizzle: XCD (bid&7) processes 2 complete images, so halo row
// sharing (each x row read by 2 blocks) stays inside one XCD's 4MB L2.
// LDS: 4 padded rows [r 0..3][px 0..129][ci 0..63] bf16 = 66,560 B, stored as
// 16B chunks with chunk' = q ^ (px&7) swizzle (write & read sides) so
// ds_read_b128 A-fragments and ds_write_b128 stores are 2-way banked (free).
__global__ __launch_bounds__(256, 2) void conv_fused(
    const float* __restrict__ x, const unsigned short* __restrict__ wq,
    const float* __restrict__ beff, float* __restrict__ out) {
  extern __shared__ __align__(16) char smem[];  // 66,560 B
  const int bid = blockIdx.x;        // 1024 blocks
  const int xcd = bid & 7;
  const int u = bid >> 3;            // 0..127
  const int n = xcd * 2 + (u >> 6);  // XCD owns images 2*xcd, 2*xcd+1
  const int h0 = (u & 63) * 2;       // output rows h0, h0+1
  const int tid = threadIdx.x;
  const int lane = tid & 63;
  const int wv = tid >> 6;
  const int rw = wv >> 1;            // which output row (0/1)
  const int pxh = (wv & 1) * 64;     // pixel half
  const int ln15 = lane & 15;
  const int lq = lane >> 4;          // 0..3: 16B ci-chunk within 64B half
  const int koff = lq << 3;          // shorts

  // ---- stage padded rows h0-1..h0+2 (h = hp-1) straight from NCHW f32 ----
  const float* xn = x + (size_t)n * (64 * 16384);

  // zero border chunks: px=0 and px=129, all 4 rows x 8 q-chunks = 64 chunks
  if (tid < 64) {
    int r = tid >> 4;          // 0..3
    int q = (tid >> 1) & 7;    // 0..7
    int px = (tid & 1) * 129;  // 0 or 129
    int swz = q ^ (px & 7);
    *(short8*)(smem + ((r * 1040 + px * 8 + swz) << 4)) = (short8)0;
  }

  // interior: 16 passes x (2 combos of (r,q)) x 128 px. Wave reads 64
  // consecutive px per dword load -> 256B coalesced; 8 ci values/thread.
  const int w128 = tid & 127;  // px-1: 0..127
  const int hi = tid >> 7;     // which (r,q) combo this half-block handles
#pragma unroll 4
  for (int pass = 0; pass < 16; ++pass) {
    const int c2 = pass * 2 + hi;  // 0..31
    const int r = c2 >> 3;         // LDS row 0..3
    const int q = c2 & 7;          // ci chunk 0..7
    const int h = h0 + r - 1;      // source row, -1..128
    short8 v = (short8)0;
    if ((unsigned)h < 128u) {      // wave-uniform predicate
      const float* sp = xn + q * 8 * 16384 + h * 128 + w128;
      float f0 = sp[0 * 16384], f1 = sp[1 * 16384], f2 = sp[2 * 16384],
            f3 = sp[3 * 16384], f4 = sp[4 * 16384], f5 = sp[5 * 16384],
            f6 = sp[6 * 16384], f7 = sp[7 * 16384];
      v[0] = (short)f2bf(f0); v[1] = (short)f2bf(f1);
      v[2] = (short)f2bf(f2); v[3] = (short)f2bf(f3);
      v[4] = (short)f2bf(f4); v[5] = (short)f2bf(f5);
      v[6] = (short)f2bf(f6); v[7] = (short)f2bf(f7);
    }
    const int px = w128 + 1;
    const int swz = q ^ (px & 7);
    *(short8*)(smem + ((r * 1040 + px * 8 + swz) << 4)) = v;
  }
  __syncthreads();

  const unsigned short* wbase = wq + ln15 * 64 + koff;

  short8 A[2][2][4], B[2][2][4];
  float4v acc[4][4] = {};  // [mf][qd]

  auto load_tap = [&](int tap, short8 Ab[2][4], short8 Bb[2][4]) {
    const int dh = tap / 3;
    const int dw = tap - dh * 3;
    const int r = rw + dh;                 // LDS row 0..3
    const int pb = pxh + ln15 + dw;        // px for mf=0 (px&7 invariant in mf)
    const int swz = lq ^ (pb & 7);         // swizzled chunk for cc2=0
    const int b0 = ((r * 130 + pb) << 7) + (swz << 4);
    const unsigned short* wp = wbase + tap * 4096;
#pragma unroll
    for (int mf = 0; mf < 4; ++mf) {       // px += 16 per mf: swizzle unchanged
      Ab[0][mf] = *(const short8*)(smem + (b0 + mf * 2048));
      Ab[1][mf] = *(const short8*)(smem + ((b0 ^ 64) + mf * 2048));  // cc2=1: chunk^4
    }
#pragma unroll
    for (int qd = 0; qd < 4; ++qd) {
      Bb[0][qd] = *(const short8*)(wp + qd * 1024);
      Bb[1][qd] = *(const short8*)(wp + qd * 1024 + 32);
    }
  };

  load_tap(0, A[0], B[0]);
#pragma unroll
  for (int tap = 0; tap < 9; ++tap) {
    const int cur = tap & 1, nxt = cur ^ 1;
    if (tap < 8) load_tap(tap + 1, A[nxt], B[nxt]);
    __builtin_amdgcn_s_setprio(1);
#pragma unroll
    for (int cc2 = 0; cc2 < 2; ++cc2)
#pragma unroll
      for (int mf = 0; mf < 4; ++mf)
#pragma unroll
        for (int qd = 0; qd < 4; ++qd)
          acc[mf][qd] = __builtin_amdgcn_mfma_f32_16x16x32_bf16(
              A[cur][cc2][mf], B[cur][cc2][qd], acc[mf][qd], 0, 0, 0);
    __builtin_amdgcn_s_setprio(0);
  }

  // epilogue: C/D layout col=lane&15 (oc), row=(lane>>4)*4+reg (pixel)
  const int rq = lane >> 4;
  float bias[4];
#pragma unroll
  for (int q = 0; q < 4; ++q) bias[q] = beff[q * 16 + ln15];
#pragma unroll
  for (int mf = 0; mf < 4; ++mf) {
#pragma unroll
    for (int qd = 0; qd < 4; ++qd) {
      float4v v = acc[mf][qd] + bias[qd];
      int oc = qd * 16 + ln15;
      float* op = out + (((n * 64 + oc) * 128 + h0 + rw) * 128 + pxh + mf * 16 + rq * 4);
      *(float4v*)op = v;
    }
  }
}

extern "C" void kernel_launch(void* const* d_in, const int* in_sizes, int n_in,
                              void* d_out, int out_size, void* d_ws, size_t ws_size,
                              hipStream_t stream) {
  const float* x = (const float*)d_in[0];
  const float* w = (const float*)d_in[1];
  const float* b = (const float*)d_in[2];
  const float* wc = (const float*)d_in[3];
  const float* bc = (const float*)d_in[4];
  const float* gate = (const float*)d_in[5];

  // ws: wq bf16[36864]=73728B | beff f32[64] @73728 | part f64[18] @73984
  unsigned short* wq = (unsigned short*)d_ws;
  float* beff = (float*)((char*)d_ws + 73728);
  double* part = (double*)((char*)d_ws + 73984);

  reduce_abs_part<<<9, 1024, 0, stream>>>(w, wc, part);
  quant_combine<<<144, 256, 0, stream>>>(w, wc, b, bc, gate, part, wq, beff);
  conv_fused<<<16 * 64, 256, 66560, stream>>>(x, wq, beff, (float*)d_out);
}

// Round 5
// 144.032 us; speedup vs baseline: 1.3844x; 1.1512x over previous
//
#include <hip/hip_runtime.h>
#include <math.h>

// ---------------------------------------------------------------------------
// FPSANConv2d: out = conv3x3(x, Qt(w)) + b + sigmoid(gate)*(conv3x3(x, Qt(w_child)) + b_child)
// Fused: W_eff = Qt(w) + g*Qt(w_child) (bf16), b_eff = b + g*b_child, ONE conv.
//
// Round 10 = Round 9 resubmit (GPUAcquisitionTimeout = infra, no verdict).
//   B (weights) moved into LDS with 1-tap-ahead ping-pong.
//   R8 evidence: MfmaUtil 10%, VGPR=108 -> compiler sank per-tap global B
//   loads to their MFMA uses; every tap exposed an L1-miss/L2 round trip
//   serialized on the acc chain (~8k cy/tap = the missing ~50us).
//   Fix (m97 structure): both MFMA operands from LDS. Per tap: issue B[t+1]
//   global->reg at tap start (covered by 620cy of MFMA), ds_write after the
//   MFMAs, one barrier. Block grown to 512 thr / 8 waves / 4 output rows so
//   A(6 rows, 129-px contiguous trick) + B ping-pong fit in 115,584B LDS.
//   Halo amp 2.0x -> 1.5x. Numerics bit-identical (same values into MFMA).
// ---------------------------------------------------------------------------

typedef __attribute__((ext_vector_type(8))) short short8;   // 8 bf16 (4 VGPRs)
typedef __attribute__((ext_vector_type(4))) float float4v;  // MFMA C/D frag

__device__ inline unsigned short f2bf(float f) {
  union { float f; unsigned u; } v; v.f = f;
  unsigned u = v.u;
  return (unsigned short)((u + 0x7FFFu + ((u >> 16) & 1u)) >> 16);  // RNE
}

// ---- k1: deterministic partial |w| sums: 9 blocks x 1024 x 4 elems ----
__global__ __launch_bounds__(1024) void reduce_abs_part(const float* __restrict__ w,
                                                        const float* __restrict__ wc,
                                                        double* __restrict__ part) {
  const int base = blockIdx.x * 4096 + threadIdx.x;
  double a = 0.0, c = 0.0;
#pragma unroll
  for (int i = 0; i < 4; ++i) {
    a += (double)fabsf(w[base + i * 1024]);
    c += (double)fabsf(wc[base + i * 1024]);
  }
#pragma unroll
  for (int off = 32; off > 0; off >>= 1) {
    a += __shfl_down(a, off);
    c += __shfl_down(c, off);
  }
  __shared__ double sa[16], sc[16];
  int wv = threadIdx.x >> 6;
  if ((threadIdx.x & 63) == 0) { sa[wv] = a; sc[wv] = c; }
  __syncthreads();
  if (threadIdx.x == 0) {
    double ta = 0.0, tc = 0.0;
#pragma unroll
    for (int i = 0; i < 16; ++i) { ta += sa[i]; tc += sc[i]; }
    part[blockIdx.x] = ta;
    part[9 + blockIdx.x] = tc;
  }
}

// ---- k2: ternary-quantize both weights, combine with gate, emit bf16 ----
// wq[tap][oc][ci], tap = kh*3+kw : ci-contiguous for 16B B-fragment loads.
__global__ void quant_combine(const float* __restrict__ w, const float* __restrict__ wc,
                              const float* __restrict__ b, const float* __restrict__ bc,
                              const float* __restrict__ gate, const double* __restrict__ part,
                              unsigned short* __restrict__ wq, float* __restrict__ beff) {
  double s0 = 0.0, s1 = 0.0;
#pragma unroll
  for (int i = 0; i < 9; ++i) { s0 += part[i]; s1 += part[9 + i]; }
  const float sw = fmaxf((float)(s0 * (1.0 / 36864.0)), 1e-5f);
  const float sc = fmaxf((float)(s1 * (1.0 / 36864.0)), 1e-5f);
  const float g = 1.0f / (1.0f + expf(-gate[0]));
  int idx = blockIdx.x * 256 + threadIdx.x;  // (tap, oc, ci)
  int tap = idx >> 12;
  int oc = (idx >> 6) & 63;
  int ci = idx & 63;
  int src = oc * 576 + ci * 9 + tap;  // OIHW flat
  float q1 = fminf(1.f, fmaxf(-1.f, rintf(w[src] / sw))) * sw;
  float q2 = fminf(1.f, fmaxf(-1.f, rintf(wc[src] / sc))) * sc;
  wq[idx] = f2bf(q1 + g * q2);
  if (idx < 64) beff[idx] = b[idx] + g * bc[idx];
}

// ---- k3: fused conv, both operands LDS-resident ----
// Block: 512 thr = 8 waves, 4 output rows x 128 px x 64 oc. Wave = 64px x 64oc.
// A in LDS: 6 input rows, stored 129 px/row CONTIGUOUSLY (px 0..128); reading
//   px=129 of row r lands on row r+1's px=0 zero-pad column (guard after row 5).
//   Chunk swizzle c' = c ^ (px&7) on write & read (bank-spread, mf-invariant).
// B in LDS: 2 x 8KB ping-pong, slot (oc, cq ^ (oc&7)); staged 1 tap ahead:
//   global->reg issued at tap start (hidden under 32 MFMAs), ds_write after
//   MFMAs, ONE __syncthreads per tap.
// XCD-ownership: XCD (bid&7) owns images 2*xcd, 2*xcd+1 (halo in one L2).
__global__ __launch_bounds__(512, 2) void conv_fused(
    const float* __restrict__ x, const unsigned short* __restrict__ wq,
    const float* __restrict__ beff, float* __restrict__ out) {
  extern __shared__ __align__(16) char smem[];  // 115,584 B
  char* Abase = smem;                  // 6,200 chunks * 16B = 99,200 B
  char* Bbase = smem + 99200;          // 2 * 8,192 B

  const int bid = blockIdx.x;          // 512 blocks
  const int xcd = bid & 7;
  const int u = bid >> 3;              // 0..63
  const int n = xcd * 2 + (u >> 5);    // image
  const int h0 = (u & 31) * 4;         // output rows h0..h0+3
  const int tid = threadIdx.x;
  const int lane = tid & 63;
  const int wv = tid >> 6;             // 0..7
  const int rw = wv >> 1;              // output row within block (0..3)
  const int pxh = (wv & 1) * 64;       // pixel half
  const int ln15 = lane & 15;
  const int lq = lane >> 4;            // 16B ci-chunk (0..3)

  const float* xn = x + (size_t)n * (64 * 16384);

  // ---- B tap-0: coalesced 16B/thread global load (issued early) ----
  const short8 b0v = *(const short8*)(wq + tid * 8);

  // ---- A borders: px=0 column (6 rows x 8 chunks) + 8 guard chunks ----
  if (tid < 56) {
    int slot = (tid < 48) ? ((tid >> 3) * 129 * 8 + (tid & 7)) : (6192 + (tid - 48));
    *(short8*)(Abase + (slot << 4)) = (short8)0;
  }

  // ---- A interior: 12 passes x 4 (r,c)-combos x 128 px ----
  const int w128 = tid & 127;          // global px 0..127
  const int hi = tid >> 7;             // 0..3
#pragma unroll 4
  for (int pass = 0; pass < 12; ++pass) {
    const int k = pass * 4 + hi;       // 0..47
    const int r = k >> 3;              // LDS row 0..5
    const int c = k & 7;               // ci chunk 0..7
    const int h = h0 + r - 1;          // source row, -1..128
    short8 v = (short8)0;
    if ((unsigned)h < 128u) {          // wave-uniform
      const float* sp = xn + c * 8 * 16384 + h * 128 + w128;
      v[0] = (short)f2bf(sp[0 * 16384]);
      v[1] = (short)f2bf(sp[1 * 16384]);
      v[2] = (short)f2bf(sp[2 * 16384]);
      v[3] = (short)f2bf(sp[3 * 16384]);
      v[4] = (short)f2bf(sp[4 * 16384]);
      v[5] = (short)f2bf(sp[5 * 16384]);
      v[6] = (short)f2bf(sp[6 * 16384]);
      v[7] = (short)f2bf(sp[7 * 16384]);
    }
    const int p = w128 + 1;            // padded px 1..128
    const int slot = (r * 129 + p) * 8 + (c ^ (p & 7));
    *(short8*)(Abase + (slot << 4)) = v;
  }

  // ---- B tap-0 swizzled LDS write ----
  const int bslot = (tid & ~7) | ((tid & 7) ^ ((tid >> 3) & 7));
  *(short8*)(Bbase + (bslot << 4)) = b0v;
  __syncthreads();

  float4v acc[4][4] = {};  // [mf][qd]

#pragma unroll
  for (int tap = 0; tap < 9; ++tap) {
    const int cb = tap & 1;
    // issue next-tap B global load FIRST (hidden under this tap's MFMAs)
    short8 btrans;
    if (tap < 8) btrans = *(const short8*)(wq + (tap + 1) * 4096 + tid * 8);

    // A fragments from LDS
    const int dh = tap / 3;
    const int dw = tap - dh * 3;
    const int r = rw + dh;             // 0..5
    const int pb = pxh + ln15 + dw;    // padded px for mf=0 (px&7 mf-invariant)
    const int a0 = (((r * 129 + pb) << 3) + (lq ^ (pb & 7))) << 4;
    short8 Ab[2][4], Bb[2][4];
#pragma unroll
    for (int mf = 0; mf < 4; ++mf) {   // px += 16 per mf: +2048B, swizzle same
      Ab[0][mf] = *(const short8*)(Abase + (a0 + mf * 2048));
      Ab[1][mf] = *(const short8*)(Abase + ((a0 ^ 64) + mf * 2048));  // chunk^4
    }
    // B fragments from LDS (swizzled slots)
#pragma unroll
    for (int qd = 0; qd < 4; ++qd) {
      const int oc = qd * 16 + ln15;   // oc&7 == ln15&7
      Bb[0][qd] = *(const short8*)(Bbase + cb * 8192 +
                                   ((oc * 8 + (lq ^ (ln15 & 7))) << 4));
      Bb[1][qd] = *(const short8*)(Bbase + cb * 8192 +
                                   ((oc * 8 + ((lq + 4) ^ (ln15 & 7))) << 4));
    }

    __builtin_amdgcn_s_setprio(1);
#pragma unroll
    for (int cc2 = 0; cc2 < 2; ++cc2)
#pragma unroll
      for (int mf = 0; mf < 4; ++mf)
#pragma unroll
        for (int qd = 0; qd < 4; ++qd)
          acc[mf][qd] = __builtin_amdgcn_mfma_f32_16x16x32_bf16(
              Ab[cc2][mf], Bb[cc2][qd], acc[mf][qd], 0, 0, 0);
    __builtin_amdgcn_s_setprio(0);

    if (tap < 8) {
      // write next-tap B into the other buffer; all waves finished reading it
      // (during tap-1) before the barrier that ended tap-1.
      *(short8*)(Bbase + (cb ^ 1) * 8192 + (bslot << 4)) = btrans;
      __syncthreads();
    }
  }

  // ---- epilogue: C/D layout col=lane&15 (oc), row=(lane>>4)*4+reg (pixel) ----
  const int rq = lane >> 4;
  float bias[4];
#pragma unroll
  for (int q = 0; q < 4; ++q) bias[q] = beff[q * 16 + ln15];
#pragma unroll
  for (int mf = 0; mf < 4; ++mf) {
#pragma unroll
    for (int qd = 0; qd < 4; ++qd) {
      float4v v = acc[mf][qd] + bias[qd];
      int oc = qd * 16 + ln15;
      float* op = out + (((n * 64 + oc) * 128 + h0 + rw) * 128 + pxh + mf * 16 + rq * 4);
      *(float4v*)op = v;
    }
  }
}

extern "C" void kernel_launch(void* const* d_in, const int* in_sizes, int n_in,
                              void* d_out, int out_size, void* d_ws, size_t ws_size,
                              hipStream_t stream) {
  const float* x = (const float*)d_in[0];
  const float* w = (const float*)d_in[1];
  const float* b = (const float*)d_in[2];
  const float* wc = (const float*)d_in[3];
  const float* bc = (const float*)d_in[4];
  const float* gate = (const float*)d_in[5];

  // ws: wq bf16[36864]=73728B | beff f32[64] @73728 | part f64[18] @73984
  unsigned short* wq = (unsigned short*)d_ws;
  float* beff = (float*)((char*)d_ws + 73728);
  double* part = (double*)((char*)d_ws + 73984);

  reduce_abs_part<<<9, 1024, 0, stream>>>(w, wc, part);
  quant_combine<<<144, 256, 0, stream>>>(w, wc, b, bc, gate, part, wq, beff);
  conv_fused<<<512, 512, 115584, stream>>>(x, wq, beff, (float*)d_out);
}